// Round 4
// baseline (619.286 us; speedup 1.0000x reference)
//
#include <hip/hip_runtime.h>

typedef _Float16 h8 __attribute__((ext_vector_type(8)));
typedef float f4 __attribute__((ext_vector_type(4)));

#define NHEADS 6
#define LOGMAX 4.6051701859880914f   // ln(100)

// kept position j (0..31) -> row index in window (0..63); kept iff (r+c) even
__device__ __forceinline__ int S_of(int j) { return ((j >> 2) << 3) + ((j & 3) << 1) + ((j >> 2) & 1); }
// complement (masked) position
__device__ __forceinline__ int SC_of(int j) { return ((j >> 2) << 3) + ((j & 3) << 1) + (1 - ((j >> 2) & 1)); }

// ---------------------------------------------------------------------------
// Pack kernel.
// qkvp: [h][nt 0..5][ks 0..5][lane][8]
//   nt: 0,1=q cols 0:16/16:32 ; 2,3=k ; 4,5=v
//   elem = qkv_w[(nt>>1)*192 + h*32 + (nt&1)*16 + (l&15)][ks*32 + (l>>4)*8 + j]
// projp: [h][nt 0..11][lane][8] = proj_w[nt*16+(l&15)][h*32 + (l>>4)*8 + j]
// biask: [h][32][32] = rel_bias_table[rel_pos_index[S(row)][S(col)]][h]
// ---------------------------------------------------------------------------
__global__ void pack_kernel(const float* __restrict__ qkv_w,
                            const float* __restrict__ proj_w,
                            const float* __restrict__ rel_bias_table,
                            const int* __restrict__ rel_pos_index,
                            _Float16* __restrict__ qkvp,
                            _Float16* __restrict__ projp,
                            float* __restrict__ biask) {
    int tid = blockIdx.x * 256 + threadIdx.x;
    const int NQ = 6 * 6 * 6 * 64;        // 13824
    const int NP = 6 * 12 * 64;           // 4608
    if (tid < NQ) {
        int l = tid & 63;
        int rest = tid >> 6;
        int ks = rest % 6;
        int nt = (rest / 6) % 6;
        int h = rest / 36;
        int o = (nt >> 1) * 192 + h * 32 + (nt & 1) * 16 + (l & 15);
        int k0 = ks * 32 + (l >> 4) * 8;
        const float* src = qkv_w + o * 192 + k0;
        _Float16* dst = qkvp + tid * 8;
#pragma unroll
        for (int j = 0; j < 8; ++j) dst[j] = (_Float16)src[j];
    } else if (tid < NQ + NP) {
        int t = tid - NQ;
        int l = t & 63;
        int rest = t >> 6;         // 0..71
        int nt = rest % 12;
        int h = rest / 12;
        int o = nt * 16 + (l & 15);
        int k0 = h * 32 + (l >> 4) * 8;
        const float* src = proj_w + o * 192 + k0;
        _Float16* dst = projp + t * 8;
#pragma unroll
        for (int j = 0; j < 8; ++j) dst[j] = (_Float16)src[j];
    } else if (tid < NQ + NP + 6 * 32 * 32) {
        int t = tid - (NQ + NP);
        int h = t >> 10;
        int jr = (t >> 5) & 31;
        int ic = t & 31;
        int rp = rel_pos_index[S_of(jr) * 64 + S_of(ic)];
        biask[t] = rel_bias_table[rp * NHEADS + h];
    }
}

// ---------------------------------------------------------------------------
// Main fused kernel: 1 block = 2 windows, 4 waves; wave (w, mh) owns 16 rows
// (m-half mh) of window w. qkv A-frags + proj accumulators live in registers
// across all heads. kn/vT double-buffered by head parity -> 1 barrier/head.
// waves_per_eu(3,3): per-wave budget ~170 regs so the allocator keeps
// xf(24 VGPR) + pacc(48 AGPR) + phase working set WITHOUT scratch spills
// (rounds 2/3 pinned 4/EU -> 64 arch VGPRs -> ~200 MB of spill write-back).
// ---------------------------------------------------------------------------
#define RS 40   // row stride (f16) for all LDS tiles: 80 B, 16B-aligned

__global__ __launch_bounds__(256) __attribute__((amdgpu_waves_per_eu(3, 3)))
void cwa_kernel(
    const float* __restrict__ x,
    const _Float16* __restrict__ qkvp,
    const _Float16* __restrict__ projp,
    const float* __restrict__ biask,
    const float* __restrict__ qkv_b,
    const float* __restrict__ proj_b,
    const float* __restrict__ logit_scale,
    float* __restrict__ out) {
    __shared__ __align__(16) _Float16 kn[2][2][32][RS];   // [parity][window]
    __shared__ __align__(16) _Float16 vT[2][2][32][RS];
    __shared__ __align__(16) _Float16 outH[2][32][RS];
    __shared__ __align__(16) _Float16 qn[4][16][RS];      // wave-private
    __shared__ __align__(16) _Float16 pl[4][16][RS];      // wave-private

    const int tid = threadIdx.x;
    const int lane = tid & 63;
    const int wave = tid >> 6;
    const int cl = lane & 15;
    const int g = lane >> 4;
    const int w0 = blockIdx.x * 2;
    const int w = wave >> 1;    // window within block
    const int mh = wave & 1;    // 16-row m-half within window

    // ---- masked rows: output = proj_b ----
    {
        int rowi = tid >> 2;   // 0..63  (2 windows x 32 masked rows)
        int sub = tid & 3;
        long base = ((long)(w0 + (rowi >> 5)) * 64 + SC_of(rowi & 31)) * 192;
#pragma unroll
        for (int i = 0; i < 12; ++i) {
            int c4 = i * 4 + sub;
            *(f4*)(out + base + c4 * 4) = *(const f4*)(proj_b + c4 * 4);
        }
    }

    // ---- load this wave's 16 x-rows into A-fragment registers (fp16) ----
    h8 xf[6];
    {
        long xbase = ((long)(w0 + w) * 64 + S_of(mh * 16 + cl)) * 192;
#pragma unroll
        for (int ks = 0; ks < 6; ++ks) {
            f4 u0 = *(const f4*)(x + xbase + ks * 32 + g * 8);
            f4 u1 = *(const f4*)(x + xbase + ks * 32 + g * 8 + 4);
            h8 hv;
            hv[0] = (_Float16)u0[0]; hv[1] = (_Float16)u0[1];
            hv[2] = (_Float16)u0[2]; hv[3] = (_Float16)u0[3];
            hv[4] = (_Float16)u1[0]; hv[5] = (_Float16)u1[1];
            hv[6] = (_Float16)u1[2]; hv[7] = (_Float16)u1[3];
            xf[ks] = hv;
        }
    }

    f4 pacc[12];
#pragma unroll
    for (int nt = 0; nt < 12; ++nt) pacc[nt] = 0.0f;

#pragma unroll 1
    for (int h = 0; h < NHEADS; ++h) {
        const int par = h & 1;
        const _Float16* qb_h = qkvp + (long)h * 6 * 6 * 64 * 8;

        // ================= Phase A: qkv GEMM, single pass (6 accumulators) ==
        {
            f4 acc[6];
#pragma unroll
            for (int nt = 0; nt < 6; ++nt) acc[nt] = 0.0f;
#pragma unroll
            for (int ks = 0; ks < 6; ++ks) {
#pragma unroll
                for (int nt = 0; nt < 6; ++nt) {
                    h8 b = *(const h8*)(qb_h + (((nt * 6 + ks) * 64 + lane) << 3));
                    acc[nt] = __builtin_amdgcn_mfma_f32_16x16x32_f16(xf[ks], b, acc[nt], 0, 0, 0);
                }
            }
            float bq0 = qkv_b[h * 32 + cl], bq1 = qkv_b[h * 32 + 16 + cl];
            float bk0 = qkv_b[192 + h * 32 + cl], bk1 = qkv_b[192 + h * 32 + 16 + cl];
            float bv0 = qkv_b[384 + h * 32 + cl], bv1 = qkv_b[384 + h * 32 + 16 + cl];
#pragma unroll
            for (int r = 0; r < 4; ++r) {
                int lr = g * 4 + r;
                // q
                float t0 = acc[0][r] + bq0, t1 = acc[1][r] + bq1;
                float ss = t0 * t0 + t1 * t1;
#pragma unroll
                for (int msk = 1; msk < 16; msk <<= 1) ss += __shfl_xor(ss, msk, 16);
                float rs = 1.0f / fmaxf(sqrtf(ss), 1e-12f);
                qn[wave][lr][cl] = (_Float16)(t0 * rs);
                qn[wave][lr][16 + cl] = (_Float16)(t1 * rs);
                // k
                t0 = acc[2][r] + bk0; t1 = acc[3][r] + bk1;
                ss = t0 * t0 + t1 * t1;
#pragma unroll
                for (int msk = 1; msk < 16; msk <<= 1) ss += __shfl_xor(ss, msk, 16);
                rs = 1.0f / fmaxf(sqrtf(ss), 1e-12f);
                kn[par][w][mh * 16 + lr][cl] = (_Float16)(t0 * rs);
                kn[par][w][mh * 16 + lr][16 + cl] = (_Float16)(t1 * rs);
                // v (store transposed: [d][kv])
                vT[par][w][cl][mh * 16 + lr] = (_Float16)(acc[4][r] + bv0);
                vT[par][w][16 + cl][mh * 16 + lr] = (_Float16)(acc[5][r] + bv1);
            }
        }
        __syncthreads();   // kn/vT[par] ready (also orders reuse vs head h-2)

        // ================= Phase B: attention (own 16 q-rows) ===============
        {
            h8 aq = *(const h8*)(&qn[wave][cl][g * 8]);
            f4 sN[2];
            sN[0] = 0.0f; sN[1] = 0.0f;
#pragma unroll
            for (int nt = 0; nt < 2; ++nt) {
                h8 bk_ = *(const h8*)(&kn[par][w][nt * 16 + cl][g * 8]);
                sN[nt] = __builtin_amdgcn_mfma_f32_16x16x32_f16(aq, bk_, sN[nt], 0, 0, 0);
            }
            float scale = __expf(fminf(logit_scale[h], LOGMAX));
            float lg[2][4];
#pragma unroll
            for (int nt = 0; nt < 2; ++nt)
#pragma unroll
                for (int r = 0; r < 4; ++r)
                    lg[nt][r] = sN[nt][r] * scale +
                                biask[h * 1024 + (mh * 16 + g * 4 + r) * 32 + nt * 16 + cl];
            float po[2][4];
#pragma unroll
            for (int r = 0; r < 4; ++r) {
                float mx = fmaxf(lg[0][r], lg[1][r]);
#pragma unroll
                for (int msk = 1; msk < 16; msk <<= 1) mx = fmaxf(mx, __shfl_xor(mx, msk, 16));
                float e0 = __expf(lg[0][r] - mx);
                float e1 = __expf(lg[1][r] - mx);
                float sm = e0 + e1;
#pragma unroll
                for (int msk = 1; msk < 16; msk <<= 1) sm += __shfl_xor(sm, msk, 16);
                float inv = 1.0f / sm;
                po[0][r] = e0 * inv; po[1][r] = e1 * inv;
            }
#pragma unroll
            for (int nt = 0; nt < 2; ++nt)
#pragma unroll
                for (int r = 0; r < 4; ++r)
                    pl[wave][g * 4 + r][nt * 16 + cl] = (_Float16)po[nt][r];
            h8 ap = *(const h8*)(&pl[wave][cl][g * 8]);
            f4 ov[2];
            ov[0] = 0.0f; ov[1] = 0.0f;
#pragma unroll
            for (int nt = 0; nt < 2; ++nt) {
                h8 bv_ = *(const h8*)(&vT[par][w][nt * 16 + cl][g * 8]);
                ov[nt] = __builtin_amdgcn_mfma_f32_16x16x32_f16(ap, bv_, ov[nt], 0, 0, 0);
            }
#pragma unroll
            for (int nt = 0; nt < 2; ++nt)
#pragma unroll
                for (int r = 0; r < 4; ++r)
                    outH[w][mh * 16 + g * 4 + r][nt * 16 + cl] = (_Float16)ov[nt][r];
        }
        // outH rows are wave-private: no barrier needed before reading them.

        // ================= Incremental proj: pacc += O_h * Wp[h] ============
        {
            h8 am = *(const h8*)(&outH[w][mh * 16 + cl][g * 8]);
            const _Float16* pp_h = projp + (long)h * 12 * 64 * 8;
#pragma unroll
            for (int nt = 0; nt < 12; ++nt) {
                h8 bp = *(const h8*)(pp_h + ((nt * 64 + lane) << 3));
                pacc[nt] = __builtin_amdgcn_mfma_f32_16x16x32_f16(am, bp, pacc[nt], 0, 0, 0);
            }
        }
        // no trailing barrier: next head writes kn/vT[par^1]; the next
        // head's own barrier orders the par-buffer reuse two heads out.
    }

    // ================= Final store: out = pacc + proj_b =================
#pragma unroll
    for (int r = 0; r < 4; ++r) {
        long grow = (long)(w0 + w) * 64 + S_of(mh * 16 + g * 4 + r);
        float* po_ = out + grow * 192 + cl;
#pragma unroll
        for (int nt = 0; nt < 12; ++nt)
            po_[nt * 16] = pacc[nt][r] + proj_b[nt * 16 + cl];
    }
}

extern "C" void kernel_launch(void* const* d_in, const int* in_sizes, int n_in,
                              void* d_out, int out_size, void* d_ws, size_t ws_size,
                              hipStream_t stream) {
    const float* x = (const float*)d_in[0];
    const float* qkv_w = (const float*)d_in[1];
    const float* qkv_b = (const float*)d_in[2];
    const float* proj_w = (const float*)d_in[3];
    const float* proj_b = (const float*)d_in[4];
    const float* logit_scale = (const float*)d_in[5];
    const float* rel_bias_table = (const float*)d_in[6];
    const int* rel_pos_index = (const int*)d_in[7];
    float* out = (float*)d_out;

    const int B = in_sizes[0] / (64 * 192);   // number of windows (8192)

    _Float16* qkvp = (_Float16*)d_ws;                 // 13824*8 f16
    _Float16* projp = qkvp + 6 * 6 * 6 * 64 * 8;      // 4608*8 f16
    float* biask = (float*)(projp + 6 * 12 * 64 * 8); // 6*32*32 f32

    pack_kernel<<<96, 256, 0, stream>>>(qkv_w, proj_w, rel_bias_table, rel_pos_index,
                                        qkvp, projp, biask);
    cwa_kernel<<<B / 2, 256, 0, stream>>>(x, qkvp, projp, biask, qkv_b, proj_b,
                                          logit_scale, out);
}

// Round 5
// 281.456 us; speedup vs baseline: 2.2003x; 2.2003x over previous
//
#include <hip/hip_runtime.h>

typedef _Float16 h8 __attribute__((ext_vector_type(8)));
typedef float f4 __attribute__((ext_vector_type(4)));

#define NHEADS 6
#define LOGMAX 4.6051701859880914f   // ln(100)

// kept position j (0..31) -> row index in window (0..63); kept iff (r+c) even
__device__ __forceinline__ int S_of(int j) { return ((j >> 2) << 3) + ((j & 3) << 1) + ((j >> 2) & 1); }
// complement (masked) position
__device__ __forceinline__ int SC_of(int j) { return ((j >> 2) << 3) + ((j & 3) << 1) + (1 - ((j >> 2) & 1)); }

// ---------------------------------------------------------------------------
// Pack kernel.
// qkvp: [h][nt 0..5][ks 0..5][lane][8]
//   nt: 0,1=q cols 0:16/16:32 ; 2,3=k ; 4,5=v
//   elem = qkv_w[(nt>>1)*192 + h*32 + (nt&1)*16 + (l&15)][ks*32 + (l>>4)*8 + j]
// projp: [h][nt 0..11][lane][8] = proj_w[nt*16+(l&15)][h*32 + (l>>4)*8 + j]
//   (h doubles as the k-block index ks for the full-K proj GEMM)
// biask: [h][32][32] = rel_bias_table[rel_pos_index[S(row)][S(col)]][h]
// ---------------------------------------------------------------------------
__global__ void pack_kernel(const float* __restrict__ qkv_w,
                            const float* __restrict__ proj_w,
                            const float* __restrict__ rel_bias_table,
                            const int* __restrict__ rel_pos_index,
                            _Float16* __restrict__ qkvp,
                            _Float16* __restrict__ projp,
                            float* __restrict__ biask) {
    int tid = blockIdx.x * 256 + threadIdx.x;
    const int NQ = 6 * 6 * 6 * 64;        // 13824
    const int NP = 6 * 12 * 64;           // 4608
    if (tid < NQ) {
        int l = tid & 63;
        int rest = tid >> 6;
        int ks = rest % 6;
        int nt = (rest / 6) % 6;
        int h = rest / 36;
        int o = (nt >> 1) * 192 + h * 32 + (nt & 1) * 16 + (l & 15);
        int k0 = ks * 32 + (l >> 4) * 8;
        const float* src = qkv_w + o * 192 + k0;
        _Float16* dst = qkvp + tid * 8;
#pragma unroll
        for (int j = 0; j < 8; ++j) dst[j] = (_Float16)src[j];
    } else if (tid < NQ + NP) {
        int t = tid - NQ;
        int l = t & 63;
        int rest = t >> 6;         // 0..71
        int nt = rest % 12;
        int h = rest / 12;
        int o = nt * 16 + (l & 15);
        int k0 = h * 32 + (l >> 4) * 8;
        const float* src = proj_w + o * 192 + k0;
        _Float16* dst = projp + t * 8;
#pragma unroll
        for (int j = 0; j < 8; ++j) dst[j] = (_Float16)src[j];
    } else if (tid < NQ + NP + 6 * 32 * 32) {
        int t = tid - (NQ + NP);
        int h = t >> 10;
        int jr = (t >> 5) & 31;
        int ic = t & 31;
        int rp = rel_pos_index[S_of(jr) * 64 + S_of(ic)];
        biask[t] = rel_bias_table[rp * NHEADS + h];
    }
}

// ---------------------------------------------------------------------------
// Main fused kernel: 1 block = 2 windows, 4 waves; wave (w, mh) owns 16 rows.
// xf (x A-frags) in registers across heads; per-head O -> shared swizzled
// outS; ONE phase-C proj GEMM at the end (accumulators live only in phase C:
// peak pressure = max over phases, not sum — round-4 lesson).
// kn/vT parity-double-buffered: 1 barrier/head + 1 before phase C.
// waves_per_eu(3,*): 170-reg budget so B-frag loads can stay in flight.
// ---------------------------------------------------------------------------
#define RS 40   // kn/vT/tmp row stride (f16): 80 B, 16B-aligned, 2-way banks

__global__ __launch_bounds__(256) __attribute__((amdgpu_waves_per_eu(3, 8)))
void cwa_kernel(
    const float* __restrict__ x,
    const _Float16* __restrict__ qkvp,
    const _Float16* __restrict__ projp,
    const float* __restrict__ biask,
    const float* __restrict__ qkv_b,
    const float* __restrict__ proj_b,
    const float* __restrict__ logit_scale,
    float* __restrict__ out) {
    __shared__ __align__(16) _Float16 kn[2][2][32][RS];   // [parity][window] 10240 B
    __shared__ __align__(16) _Float16 vT[2][2][32][RS];   // 10240 B
    __shared__ __align__(16) _Float16 tmp[4][16][RS];     // wave-private q then p, 5120 B
    __shared__ __align__(16) _Float16 outS[64 * 192];     // swizzled, 24576 B
    // total 50176 B -> 3 blocks/CU

    const int tid = threadIdx.x;
    const int lane = tid & 63;
    const int wave = tid >> 6;
    const int cl = lane & 15;
    const int g = lane >> 4;
    const int w0 = blockIdx.x * 2;
    const int w = wave >> 1;    // window within block
    const int mh = wave & 1;    // 16-row m-half within window

    // ---- masked rows: output = proj_b ----
    {
        int rowi = tid >> 2;   // 0..63  (2 windows x 32 masked rows)
        int sub = tid & 3;
        long base = ((long)(w0 + (rowi >> 5)) * 64 + SC_of(rowi & 31)) * 192;
#pragma unroll
        for (int i = 0; i < 12; ++i) {
            int c4 = i * 4 + sub;
            *(f4*)(out + base + c4 * 4) = *(const f4*)(proj_b + c4 * 4);
        }
    }

    // ---- load this wave's 16 x-rows into A-fragment registers (fp16) ----
    h8 xf[6];
    {
        long xbase = ((long)(w0 + w) * 64 + S_of(mh * 16 + cl)) * 192;
#pragma unroll
        for (int ks = 0; ks < 6; ++ks) {
            f4 u0 = *(const f4*)(x + xbase + ks * 32 + g * 8);
            f4 u1 = *(const f4*)(x + xbase + ks * 32 + g * 8 + 4);
            h8 hv;
            hv[0] = (_Float16)u0[0]; hv[1] = (_Float16)u0[1];
            hv[2] = (_Float16)u0[2]; hv[3] = (_Float16)u0[3];
            hv[4] = (_Float16)u1[0]; hv[5] = (_Float16)u1[1];
            hv[6] = (_Float16)u1[2]; hv[7] = (_Float16)u1[3];
            xf[ks] = hv;
        }
    }

#pragma unroll 1
    for (int h = 0; h < NHEADS; ++h) {
        const int par = h & 1;
        const _Float16* qb_h = qkvp + (long)h * 6 * 6 * 64 * 8;

        // ================= Phase A: qkv GEMM, single pass (6 accumulators) ==
        {
            f4 acc[6];
#pragma unroll
            for (int nt = 0; nt < 6; ++nt) acc[nt] = 0.0f;
#pragma unroll
            for (int ks = 0; ks < 6; ++ks) {
#pragma unroll
                for (int nt = 0; nt < 6; ++nt) {
                    h8 b = *(const h8*)(qb_h + (((nt * 6 + ks) * 64 + lane) << 3));
                    acc[nt] = __builtin_amdgcn_mfma_f32_16x16x32_f16(xf[ks], b, acc[nt], 0, 0, 0);
                }
            }
            float bq0 = qkv_b[h * 32 + cl], bq1 = qkv_b[h * 32 + 16 + cl];
            float bk0 = qkv_b[192 + h * 32 + cl], bk1 = qkv_b[192 + h * 32 + 16 + cl];
            float bv0 = qkv_b[384 + h * 32 + cl], bv1 = qkv_b[384 + h * 32 + 16 + cl];
#pragma unroll
            for (int r = 0; r < 4; ++r) {
                int lr = g * 4 + r;
                // q -> tmp (wave-private)
                float t0 = acc[0][r] + bq0, t1 = acc[1][r] + bq1;
                float ss = t0 * t0 + t1 * t1;
#pragma unroll
                for (int msk = 1; msk < 16; msk <<= 1) ss += __shfl_xor(ss, msk, 16);
                float rs = 1.0f / fmaxf(sqrtf(ss), 1e-12f);
                tmp[wave][lr][cl] = (_Float16)(t0 * rs);
                tmp[wave][lr][16 + cl] = (_Float16)(t1 * rs);
                // k
                t0 = acc[2][r] + bk0; t1 = acc[3][r] + bk1;
                ss = t0 * t0 + t1 * t1;
#pragma unroll
                for (int msk = 1; msk < 16; msk <<= 1) ss += __shfl_xor(ss, msk, 16);
                rs = 1.0f / fmaxf(sqrtf(ss), 1e-12f);
                kn[par][w][mh * 16 + lr][cl] = (_Float16)(t0 * rs);
                kn[par][w][mh * 16 + lr][16 + cl] = (_Float16)(t1 * rs);
                // v (store transposed: [d][kv])
                vT[par][w][cl][mh * 16 + lr] = (_Float16)(acc[4][r] + bv0);
                vT[par][w][16 + cl][mh * 16 + lr] = (_Float16)(acc[5][r] + bv1);
            }
        }
        __syncthreads();   // kn/vT[par] ready (also orders reuse vs head h-2)

        // ================= Phase B: attention (own 16 q-rows) ===============
        {
            h8 aq = *(const h8*)(&tmp[wave][cl][g * 8]);
            f4 sN[2];
            sN[0] = 0.0f; sN[1] = 0.0f;
#pragma unroll
            for (int nt = 0; nt < 2; ++nt) {
                h8 bk_ = *(const h8*)(&kn[par][w][nt * 16 + cl][g * 8]);
                sN[nt] = __builtin_amdgcn_mfma_f32_16x16x32_f16(aq, bk_, sN[nt], 0, 0, 0);
            }
            float scale = __expf(fminf(logit_scale[h], LOGMAX));
            float lg[2][4];
#pragma unroll
            for (int nt = 0; nt < 2; ++nt)
#pragma unroll
                for (int r = 0; r < 4; ++r)
                    lg[nt][r] = sN[nt][r] * scale +
                                biask[h * 1024 + (mh * 16 + g * 4 + r) * 32 + nt * 16 + cl];
            float po[2][4];
#pragma unroll
            for (int r = 0; r < 4; ++r) {
                float mx = fmaxf(lg[0][r], lg[1][r]);
#pragma unroll
                for (int msk = 1; msk < 16; msk <<= 1) mx = fmaxf(mx, __shfl_xor(mx, msk, 16));
                float e0 = __expf(lg[0][r] - mx);
                float e1 = __expf(lg[1][r] - mx);
                float sm = e0 + e1;
#pragma unroll
                for (int msk = 1; msk < 16; msk <<= 1) sm += __shfl_xor(sm, msk, 16);
                float inv = 1.0f / sm;
                po[0][r] = e0 * inv; po[1][r] = e1 * inv;
            }
            // p -> tmp (reuse of q buffer; LDS ops are in-order per wave,
            // and aq was read before these writes in program order)
#pragma unroll
            for (int nt = 0; nt < 2; ++nt)
#pragma unroll
                for (int r = 0; r < 4; ++r)
                    tmp[wave][g * 4 + r][nt * 16 + cl] = (_Float16)po[nt][r];
            h8 ap = *(const h8*)(&tmp[wave][cl][g * 8]);
            f4 ov[2];
            ov[0] = 0.0f; ov[1] = 0.0f;
#pragma unroll
            for (int nt = 0; nt < 2; ++nt) {
                h8 bv_ = *(const h8*)(&vT[par][w][nt * 16 + cl][g * 8]);
                ov[nt] = __builtin_amdgcn_mfma_f32_16x16x32_f16(ap, bv_, ov[nt], 0, 0, 0);
            }
            // O -> outS, swizzled (row-private to this wave: no barrier)
#pragma unroll
            for (int nt = 0; nt < 2; ++nt)
#pragma unroll
                for (int r = 0; r < 4; ++r) {
                    int row = w * 32 + mh * 16 + g * 4 + r;
                    int boff = (row * 384 + (h * 32 + nt * 16 + cl) * 2) ^ ((row & 7) << 4);
                    *(_Float16*)((char*)outS + boff) = (_Float16)ov[nt][r];
                }
        }
        // no trailing barrier: next head writes kn/vT[par^1]; its own barrier
        // orders the parity-buffer reuse two heads out.
    }
    __syncthreads();   // outS complete (all waves, all heads)

    // ================= Phase C: proj GEMM (wave = (row-half wm, col-half wn))
    {
        const int wm = wave >> 1;   // 32 outS rows (= window wm)
        const int wn = wave & 1;    // 96 output cols
        f4 pacc0[6], pacc1[6];
#pragma unroll
        for (int nt = 0; nt < 6; ++nt) { pacc0[nt] = 0.0f; pacc1[nt] = 0.0f; }
#pragma unroll
        for (int ks = 0; ks < 6; ++ks) {
            int r0 = wm * 32 + cl;
            int r1 = wm * 32 + 16 + cl;
            h8 a0 = *(const h8*)((char*)outS + ((r0 * 384 + ks * 64 + g * 16) ^ ((r0 & 7) << 4)));
            h8 a1 = *(const h8*)((char*)outS + ((r1 * 384 + ks * 64 + g * 16) ^ ((r1 & 7) << 4)));
#pragma unroll
            for (int nt = 0; nt < 6; ++nt) {
                h8 b = *(const h8*)(projp + (((ks * 12 + wn * 6 + nt) * 64 + lane) << 3));
                pacc0[nt] = __builtin_amdgcn_mfma_f32_16x16x32_f16(a0, b, pacc0[nt], 0, 0, 0);
                pacc1[nt] = __builtin_amdgcn_mfma_f32_16x16x32_f16(a1, b, pacc1[nt], 0, 0, 0);
            }
        }
#pragma unroll
        for (int m = 0; m < 2; ++m) {
            const f4* pm = m ? pacc1 : pacc0;
#pragma unroll
            for (int r = 0; r < 4; ++r) {
                int rl = m * 16 + g * 4 + r;   // local row in window wm
                long grow = (long)(w0 + wm) * 64 + S_of(rl);
                float* po_ = out + grow * 192 + wn * 96 + cl;
#pragma unroll
                for (int nt = 0; nt < 6; ++nt)
                    po_[nt * 16] = pm[nt][r] + proj_b[wn * 96 + nt * 16 + cl];
            }
        }
    }
}

extern "C" void kernel_launch(void* const* d_in, const int* in_sizes, int n_in,
                              void* d_out, int out_size, void* d_ws, size_t ws_size,
                              hipStream_t stream) {
    const float* x = (const float*)d_in[0];
    const float* qkv_w = (const float*)d_in[1];
    const float* qkv_b = (const float*)d_in[2];
    const float* proj_w = (const float*)d_in[3];
    const float* proj_b = (const float*)d_in[4];
    const float* logit_scale = (const float*)d_in[5];
    const float* rel_bias_table = (const float*)d_in[6];
    const int* rel_pos_index = (const int*)d_in[7];
    float* out = (float*)d_out;

    const int B = in_sizes[0] / (64 * 192);   // number of windows (8192)

    _Float16* qkvp = (_Float16*)d_ws;                 // 13824*8 f16
    _Float16* projp = qkvp + 6 * 6 * 6 * 64 * 8;      // 4608*8 f16
    float* biask = (float*)(projp + 6 * 12 * 64 * 8); // 6*32*32 f32

    pack_kernel<<<96, 256, 0, stream>>>(qkv_w, proj_w, rel_bias_table, rel_pos_index,
                                        qkvp, projp, biask);
    cwa_kernel<<<B / 2, 256, 0, stream>>>(x, qkvp, projp, biask, qkv_b, proj_b,
                                          logit_scale, out);
}

// Round 6
// 246.055 us; speedup vs baseline: 2.5169x; 1.1439x over previous
//
#include <hip/hip_runtime.h>

typedef _Float16 h8 __attribute__((ext_vector_type(8)));
typedef _Float16 h2 __attribute__((ext_vector_type(2)));
typedef float f4 __attribute__((ext_vector_type(4)));

#define NHEADS 6
#define LOGMAX 4.6051701859880914f   // ln(100)

// kept position j (0..31) -> row index in window (0..63); kept iff (r+c) even
__device__ __forceinline__ int S_of(int j) { return ((j >> 2) << 3) + ((j & 3) << 1) + ((j >> 2) & 1); }
// complement (masked) position
__device__ __forceinline__ int SC_of(int j) { return ((j >> 2) << 3) + ((j & 3) << 1) + (1 - ((j >> 2) & 1)); }

// 16-lane (DPP row) reductions on the VALU pipe — replaces ds_swizzle shuffles.
template <int CTRL>
__device__ __forceinline__ float dpp_mov(float x) {
    return __builtin_bit_cast(float,
        __builtin_amdgcn_update_dpp(0, __builtin_bit_cast(int, x), CTRL, 0xF, 0xF, true));
}
__device__ __forceinline__ float rowsum16(float x) {
    x += dpp_mov<0x121>(x);   // row_ror:1
    x += dpp_mov<0x122>(x);   // row_ror:2
    x += dpp_mov<0x124>(x);   // row_ror:4
    x += dpp_mov<0x128>(x);   // row_ror:8
    return x;
}
__device__ __forceinline__ float rowmax16(float x) {
    x = fmaxf(x, dpp_mov<0x121>(x));
    x = fmaxf(x, dpp_mov<0x122>(x));
    x = fmaxf(x, dpp_mov<0x124>(x));
    x = fmaxf(x, dpp_mov<0x128>(x));
    return x;
}
__device__ __forceinline__ unsigned pack2(float a, float b) {
    h2 v; v[0] = (_Float16)a; v[1] = (_Float16)b;   // RTE casts + v_pack
    return __builtin_bit_cast(unsigned, v);
}

// ---------------------------------------------------------------------------
// Pack kernel.
// qkvp: [h][nt 0..5][ks 0..5][lane][8]   (k-dim = input feature, natural order)
//   nt: 0,1=q cols 0:16/16:32 ; 2,3=k ; 4,5=v
//   elem = qkv_w[(nt>>1)*192 + h*32 + (nt&1)*16 + (l&15)][ks*32 + (l>>4)*8 + j]
// projp: [ksblk=h 0..5][nt 0..11][lane][8], k-dim PAIR-INTERLEAVED within each
//   32-feature block: pi-pos p <-> feature h*32 + (p>>1) + ((p&1)<<4)
// biask: [h][32][32] = rel_bias_table[rel_pos_index[S(row)][S(col)]][h]
// ---------------------------------------------------------------------------
__global__ void pack_kernel(const float* __restrict__ qkv_w,
                            const float* __restrict__ proj_w,
                            const float* __restrict__ rel_bias_table,
                            const int* __restrict__ rel_pos_index,
                            _Float16* __restrict__ qkvp,
                            _Float16* __restrict__ projp,
                            float* __restrict__ biask) {
    int tid = blockIdx.x * 256 + threadIdx.x;
    const int NQ = 6 * 6 * 6 * 64;        // 13824
    const int NP = 6 * 12 * 64;           // 4608
    if (tid < NQ) {
        int l = tid & 63;
        int rest = tid >> 6;
        int ks = rest % 6;
        int nt = (rest / 6) % 6;
        int h = rest / 36;
        int o = (nt >> 1) * 192 + h * 32 + (nt & 1) * 16 + (l & 15);
        int k0 = ks * 32 + (l >> 4) * 8;
        const float* src = qkv_w + o * 192 + k0;
        _Float16* dst = qkvp + tid * 8;
#pragma unroll
        for (int j = 0; j < 8; ++j) dst[j] = (_Float16)src[j];
    } else if (tid < NQ + NP) {
        int t = tid - NQ;
        int l = t & 63;
        int rest = t >> 6;         // 0..71
        int nt = rest % 12;
        int h = rest / 12;         // k-block (head)
        int o = nt * 16 + (l & 15);
        const float* srcrow = proj_w + o * 192 + h * 32;
        _Float16* dst = projp + t * 8;
        int p0 = (l >> 4) * 8;
#pragma unroll
        for (int j = 0; j < 8; ++j) {
            int p = p0 + j;
            dst[j] = (_Float16)srcrow[(p >> 1) + ((p & 1) << 4)];
        }
    } else if (tid < NQ + NP + 6 * 32 * 32) {
        int t = tid - (NQ + NP);
        int h = t >> 10;
        int jr = (t >> 5) & 31;
        int ic = t & 31;
        int rp = rel_pos_index[S_of(jr) * 64 + S_of(ic)];
        biask[t] = rel_bias_table[rp * NHEADS + h];
    }
}

// ---------------------------------------------------------------------------
// Main fused kernel: 1 block = 2 windows, 4 waves; wave (w, mh) owns 16 rows.
// DPP reductions (VALU) for norms/softmax; pair-interleaved k-dim layouts so
// q/k/p/outS LDS writes are packed b32; kn/vT single-buffered (barriers
// bracket ONLY the 16 LDS stores); LDS = 40960 B -> 4 blocks/CU, 16 waves.
// ---------------------------------------------------------------------------
__global__ __launch_bounds__(256) __attribute__((amdgpu_waves_per_eu(4, 8)))
void cwa_kernel(
    const float* __restrict__ x,
    const _Float16* __restrict__ qkvp,
    const _Float16* __restrict__ projp,
    const float* __restrict__ biask,
    const float* __restrict__ qkv_b,
    const float* __restrict__ proj_b,
    const float* __restrict__ logit_scale,
    float* __restrict__ out) {
    __shared__ __align__(16) unsigned knu[2][32][20];   // [win][kv][d-pair] 5120 B
    __shared__ __align__(16) _Float16 vT[2][32][40];    // [win][d][kv-pi]   5120 B
    __shared__ __align__(16) unsigned tmpu[4][16][20];  // wave-private q/p  5120 B
    __shared__ __align__(16) unsigned outSu[64][100];   // [row][f-pair]    25600 B
    // total 40960 B -> exactly 4 blocks/CU

    const int tid = threadIdx.x;
    const int lane = tid & 63;
    const int wave = tid >> 6;
    const int cl = lane & 15;
    const int g = lane >> 4;
    const int w0 = blockIdx.x * 2;
    const int w = wave >> 1;    // window within block
    const int mh = wave & 1;    // 16-row m-half within window

    // ---- masked rows: output = proj_b ----
    {
        int rowi = tid >> 2;   // 0..63  (2 windows x 32 masked rows)
        int sub = tid & 3;
        long base = ((long)(w0 + (rowi >> 5)) * 64 + SC_of(rowi & 31)) * 192;
#pragma unroll
        for (int i = 0; i < 12; ++i) {
            int c4 = i * 4 + sub;
            *(f4*)(out + base + c4 * 4) = *(const f4*)(proj_b + c4 * 4);
        }
    }

    // ---- load this wave's 16 x-rows into A-fragment registers (fp16) ----
    h8 xf[6];
    {
        long xbase = ((long)(w0 + w) * 64 + S_of(mh * 16 + cl)) * 192;
#pragma unroll
        for (int ks = 0; ks < 6; ++ks) {
            f4 u0 = *(const f4*)(x + xbase + ks * 32 + g * 8);
            f4 u1 = *(const f4*)(x + xbase + ks * 32 + g * 8 + 4);
            h8 hv;
            hv[0] = (_Float16)u0[0]; hv[1] = (_Float16)u0[1];
            hv[2] = (_Float16)u0[2]; hv[3] = (_Float16)u0[3];
            hv[4] = (_Float16)u1[0]; hv[5] = (_Float16)u1[1];
            hv[6] = (_Float16)u1[2]; hv[7] = (_Float16)u1[3];
            xf[ks] = hv;
        }
    }

#pragma unroll 1
    for (int h = 0; h < NHEADS; ++h) {
        const _Float16* qb_h = qkvp + (long)h * 6 * 6 * 64 * 8;

        // ================= Phase A: qkv GEMM (6 accumulators) ===============
        f4 acc[6];
#pragma unroll
        for (int nt = 0; nt < 6; ++nt) acc[nt] = 0.0f;
#pragma unroll
        for (int ks = 0; ks < 6; ++ks) {
#pragma unroll
            for (int nt = 0; nt < 6; ++nt) {
                h8 b = *(const h8*)(qb_h + (((nt * 6 + ks) * 64 + lane) << 3));
                acc[nt] = __builtin_amdgcn_mfma_f32_16x16x32_f16(xf[ks], b, acc[nt], 0, 0, 0);
            }
        }
        // ---- epilogue compute (registers only, DPP reductions) ----
        float bq0 = qkv_b[h * 32 + cl], bq1 = qkv_b[h * 32 + 16 + cl];
        float bk0 = qkv_b[192 + h * 32 + cl], bk1 = qkv_b[192 + h * 32 + 16 + cl];
        float bv0 = qkv_b[384 + h * 32 + cl], bv1 = qkv_b[384 + h * 32 + 16 + cl];
        unsigned qw[4], kw[4];
        float vv0[4], vv1[4];
#pragma unroll
        for (int r = 0; r < 4; ++r) {
            float t0 = acc[0][r] + bq0, t1 = acc[1][r] + bq1;
            float ss = rowsum16(t0 * t0 + t1 * t1);
            float rs = 1.0f / fmaxf(sqrtf(ss), 1e-12f);
            qw[r] = pack2(t0 * rs, t1 * rs);
            t0 = acc[2][r] + bk0; t1 = acc[3][r] + bk1;
            ss = rowsum16(t0 * t0 + t1 * t1);
            rs = 1.0f / fmaxf(sqrtf(ss), 1e-12f);
            kw[r] = pack2(t0 * rs, t1 * rs);
            vv0[r] = acc[4][r] + bv0;
            vv1[r] = acc[5][r] + bv1;
        }
        __syncthreads();   // all waves done READING kn/vT of head h-1
#pragma unroll
        for (int r = 0; r < 4; ++r) {
            int q = g * 4 + r;            // row within this wave's 16
            tmpu[wave][q][cl] = qw[r];
            knu[w][mh * 16 + q][cl] = kw[r];
            int kvpos = 2 * q + mh;       // kv pair-interleave position
            vT[w][cl][kvpos] = (_Float16)vv0[r];
            vT[w][16 + cl][kvpos] = (_Float16)vv1[r];
        }
        __syncthreads();   // kn/vT ready for phase B

        // ================= Phase B: attention (own 16 q-rows) ===============
        {
            h8 aq = *(const h8*)(&tmpu[wave][cl][g * 4]);
            f4 sN[2];
            sN[0] = 0.0f; sN[1] = 0.0f;
#pragma unroll
            for (int nt = 0; nt < 2; ++nt) {
                h8 bk_ = *(const h8*)(&knu[w][nt * 16 + cl][g * 4]);
                sN[nt] = __builtin_amdgcn_mfma_f32_16x16x32_f16(aq, bk_, sN[nt], 0, 0, 0);
            }
            float scale = __expf(fminf(logit_scale[h], LOGMAX));
            float lg[2][4];
#pragma unroll
            for (int nt = 0; nt < 2; ++nt)
#pragma unroll
                for (int r = 0; r < 4; ++r)
                    lg[nt][r] = sN[nt][r] * scale +
                                biask[h * 1024 + (mh * 16 + g * 4 + r) * 32 + nt * 16 + cl];
            unsigned pw[4];
#pragma unroll
            for (int r = 0; r < 4; ++r) {
                float mx = rowmax16(fmaxf(lg[0][r], lg[1][r]));
                float e0 = __expf(lg[0][r] - mx);
                float e1 = __expf(lg[1][r] - mx);
                float inv = 1.0f / rowsum16(e0 + e1);
                pw[r] = pack2(e0 * inv, e1 * inv);
            }
#pragma unroll
            for (int r = 0; r < 4; ++r)
                tmpu[wave][g * 4 + r][cl] = pw[r];
            h8 ap = *(const h8*)(&tmpu[wave][cl][g * 4]);
            f4 ov[2];
            ov[0] = 0.0f; ov[1] = 0.0f;
#pragma unroll
            for (int nt = 0; nt < 2; ++nt) {
                h8 bv_ = *(const h8*)(&vT[w][nt * 16 + cl][g * 8]);
                ov[nt] = __builtin_amdgcn_mfma_f32_16x16x32_f16(ap, bv_, ov[nt], 0, 0, 0);
            }
            // packed O write: pair (col, col+16) within this head's 32 f-cols
#pragma unroll
            for (int r = 0; r < 4; ++r)
                outSu[w * 32 + mh * 16 + g * 4 + r][h * 16 + cl] = pack2(ov[0][r], ov[1][r]);
        }
        // next head's A-GEMM touches no shared LDS; its bar1 orders kn/vT reuse
    }
    __syncthreads();   // outSu complete

    // ======== Phase C: proj GEMM, 2 passes of 3 n-tiles (reg-peak cap) ======
    {
        const int wm = wave >> 1;   // window (32 outS rows)
        const int wn = wave & 1;    // 96-col half
        const int r0 = wm * 32 + cl;
        const int r1 = wm * 32 + 16 + cl;
#pragma unroll 1
        for (int pass = 0; pass < 2; ++pass) {
            f4 pa0[3], pa1[3];
#pragma unroll
            for (int nt = 0; nt < 3; ++nt) { pa0[nt] = 0.0f; pa1[nt] = 0.0f; }
#pragma unroll
            for (int ks = 0; ks < 6; ++ks) {
                h8 a0 = *(const h8*)(&outSu[r0][ks * 16 + g * 4]);
                h8 a1 = *(const h8*)(&outSu[r1][ks * 16 + g * 4]);
#pragma unroll
                for (int nt = 0; nt < 3; ++nt) {
                    int ntg = wn * 6 + pass * 3 + nt;
                    h8 b = *(const h8*)(projp + (((ks * 12 + ntg) * 64 + lane) << 3));
                    pa0[nt] = __builtin_amdgcn_mfma_f32_16x16x32_f16(a0, b, pa0[nt], 0, 0, 0);
                    pa1[nt] = __builtin_amdgcn_mfma_f32_16x16x32_f16(a1, b, pa1[nt], 0, 0, 0);
                }
            }
#pragma unroll
            for (int m = 0; m < 2; ++m) {
                const f4* pm = m ? pa1 : pa0;
#pragma unroll
                for (int r = 0; r < 4; ++r) {
                    int rl = m * 16 + g * 4 + r;   // local row in window wm
                    long grow = (long)(w0 + wm) * 64 + S_of(rl);
                    float* po_ = out + grow * 192 + wn * 96 + pass * 48 + cl;
#pragma unroll
                    for (int nt = 0; nt < 3; ++nt)
                        po_[nt * 16] = pm[nt][r] + proj_b[wn * 96 + pass * 48 + nt * 16 + cl];
                }
            }
        }
    }
}

extern "C" void kernel_launch(void* const* d_in, const int* in_sizes, int n_in,
                              void* d_out, int out_size, void* d_ws, size_t ws_size,
                              hipStream_t stream) {
    const float* x = (const float*)d_in[0];
    const float* qkv_w = (const float*)d_in[1];
    const float* qkv_b = (const float*)d_in[2];
    const float* proj_w = (const float*)d_in[3];
    const float* proj_b = (const float*)d_in[4];
    const float* logit_scale = (const float*)d_in[5];
    const float* rel_bias_table = (const float*)d_in[6];
    const int* rel_pos_index = (const int*)d_in[7];
    float* out = (float*)d_out;

    const int B = in_sizes[0] / (64 * 192);   // number of windows (8192)

    _Float16* qkvp = (_Float16*)d_ws;                 // 13824*8 f16
    _Float16* projp = qkvp + 6 * 6 * 6 * 64 * 8;      // 4608*8 f16
    float* biask = (float*)(projp + 6 * 12 * 64 * 8); // 6*32*32 f32

    pack_kernel<<<96, 256, 0, stream>>>(qkv_w, proj_w, rel_bias_table, rel_pos_index,
                                        qkvp, projp, biask);
    cwa_kernel<<<B / 2, 256, 0, stream>>>(x, qkvp, projp, biask, qkv_b, proj_b,
                                          logit_scale, out);
}